// Round 1
// baseline (395.955 us; speedup 1.0000x reference)
//
#include <hip/hip_runtime.h>
#include <hip/hip_bf16.h>

typedef _Float16 half8 __attribute__((ext_vector_type(8)));
typedef _Float16 half4 __attribute__((ext_vector_type(4)));
typedef float f32x4 __attribute__((ext_vector_type(4)));

#define NTOK 4096
#define CDIM 256

// ---------------------------------------------------------------------------
// Kernel 1: projections.  Q,K stored token-major [bs][N][C] fp16;
// V stored channel-major [bs][C][N] fp16.  bs = b*2 + s.
// q[n][d] = sum_c x[b][c][n] * W[d][c] + bias[d]
// ---------------------------------------------------------------------------
__global__ __launch_bounds__(256, 2) void proj_kernel(
    const float* __restrict__ x1, const float* __restrict__ x2,
    const float* __restrict__ Wq, const float* __restrict__ bq,
    const float* __restrict__ Wk, const float* __restrict__ bk,
    const float* __restrict__ Wv, const float* __restrict__ bv,
    _Float16* __restrict__ Qh, _Float16* __restrict__ Kh,
    _Float16* __restrict__ Vt)
{
    __shared__ __align__(16) _Float16 Xl[64][264];  // [n][c], +8 pad
    __shared__ __align__(16) _Float16 Wl[64][264];  // [d][c], +8 pad
    __shared__ __align__(16) _Float16 Ol[64][68];   // staging for output tile

    const int t = threadIdx.x;
    const int lane = t & 63;
    const int w = t >> 6;
    const int bs = blockIdx.x >> 6;      // 0..7
    const int ntile = blockIdx.x & 63;
    const int n0 = ntile * 64;
    const int s = bs & 1, b = bs >> 1;

    const float* x = (s ? x2 : x1) + (size_t)b * CDIM * NTOK;

    // stage X tile transposed: Xl[n][c] = x[c][n0+n], fp32 -> fp16
#pragma unroll
    for (int i = 0; i < 16; i++) {
        int id = t + 256 * i;
        int c = id >> 4, n4 = (id & 15) * 4;
        float4 v = *(const float4*)(x + (size_t)c * NTOK + n0 + n4);
        Xl[n4 + 0][c] = (_Float16)v.x;
        Xl[n4 + 1][c] = (_Float16)v.y;
        Xl[n4 + 2][c] = (_Float16)v.z;
        Xl[n4 + 3][c] = (_Float16)v.w;
    }

    for (int proj = 0; proj < 3; proj++) {
        const float* Wp = proj == 0 ? Wq : (proj == 1 ? Wk : Wv);
        const float* bp = proj == 0 ? bq : (proj == 1 ? bk : bv);
        for (int dt = 0; dt < 4; dt++) {
            const int d0 = dt * 64;
            __syncthreads();   // Wl/Ol free from previous combo
            // stage W tile [64 d][256 c]
#pragma unroll
            for (int i = 0; i < 16; i++) {
                int id = t + 256 * i;
                int d = id >> 6, c4 = (id & 63) * 4;
                float4 v = *(const float4*)(Wp + (size_t)(d0 + d) * CDIM + c4);
                half4 h = { (_Float16)v.x, (_Float16)v.y, (_Float16)v.z, (_Float16)v.w };
                *(half4*)&Wl[d][c4] = h;
            }
            __syncthreads();

            // wave w owns d rows [16w, 16w+16); 4 n-tiles of 16
            f32x4 acc[4];
            const f32x4 fz = {0.f, 0.f, 0.f, 0.f};
#pragma unroll
            for (int nt = 0; nt < 4; nt++) acc[nt] = fz;
#pragma unroll
            for (int cc = 0; cc < 8; cc++) {
                half8 wf = *(const half8*)&Wl[16 * w + (lane & 15)][cc * 32 + (lane >> 4) * 8];
#pragma unroll
                for (int nt = 0; nt < 4; nt++) {
                    half8 xf = *(const half8*)&Xl[nt * 16 + (lane & 15)][cc * 32 + (lane >> 4) * 8];
                    acc[nt] = __builtin_amdgcn_mfma_f32_16x16x32_f16(wf, xf, acc[nt], 0, 0, 0);
                }
            }
            // bias + write to Ol in target orientation
#pragma unroll
            for (int r = 0; r < 4; r++) {
                float bias = bp[d0 + 16 * w + (lane >> 4) * 4 + r];
#pragma unroll
                for (int nt = 0; nt < 4; nt++) {
                    _Float16 hv = (_Float16)(acc[nt][r] + bias);
                    if (proj < 2) Ol[nt * 16 + (lane & 15)][16 * w + (lane >> 4) * 4 + r] = hv;
                    else          Ol[16 * w + (lane >> 4) * 4 + r][nt * 16 + (lane & 15)] = hv;
                }
            }
            __syncthreads();
            // coalesced store of the 64x64 tile
            _Float16* dst;
            size_t stride;
            if (proj == 0)      { dst = Qh + ((size_t)bs * NTOK + n0) * CDIM + d0; stride = CDIM; }
            else if (proj == 1) { dst = Kh + ((size_t)bs * NTOK + n0) * CDIM + d0; stride = CDIM; }
            else                { dst = Vt + ((size_t)bs * CDIM + d0) * NTOK + n0; stride = NTOK; }
#pragma unroll
            for (int i = 0; i < 4; i++) {
                int id = t + 256 * i;
                int row = id >> 4, c4 = (id & 15) * 4;
                *(half4*)(dst + (size_t)row * stride + c4) = *(const half4*)&Ol[row][c4];
            }
        }
    }
}

// ---------------------------------------------------------------------------
// Kernel 2: flash attention.  Block = (b, s, q-tile of 64 tokens), 4 waves.
// Wave owns 16 q-rows.  K from stream s^1, V from stream s.
// Output: out[(s*4+b)][c][n] = O[n][c]  (fp32)
// ---------------------------------------------------------------------------
__global__ __launch_bounds__(256, 2) void flash_kernel(
    const _Float16* __restrict__ Qh, const _Float16* __restrict__ Kh,
    const _Float16* __restrict__ Vt, float* __restrict__ out)
{
    __shared__ __align__(16) char smem[79872];
    auto Kl = (_Float16(*)[264])smem;               // [64 m][256 c] +8 pad
    auto Vl = (_Float16(*)[72])(smem + 33792);      // [256 c][64 m] +8 pad
    auto Pl = (_Float16(*)[72])(smem + 70656);      // [64 n][64 m]  +8 pad
    auto Ol = (float(*)[68])smem;                   // reuse: [256 c][64 n] +4 pad

    const int t = threadIdx.x, lane = t & 63, w = t >> 6;
    // XCD-bijective swizzle: 512 % 8 == 0; each XCD gets one (b,s) pair
    const int orig = blockIdx.x;
    const int bid = (orig & 7) * 64 + (orig >> 3);
    const int qt = bid & 63;
    const int bs = bid >> 6;
    const int s = bs & 1, b = bs >> 1;
    const int n0 = qt * 64;

    // hoist Q fragments (wave rows n0+16w .. +15)
    const _Float16* qptr = Qh + ((size_t)bs * NTOK + n0 + 16 * w + (lane & 15)) * CDIM + (lane >> 4) * 8;
    half8 qf[8];
#pragma unroll
    for (int cc = 0; cc < 8; cc++) qf[cc] = *(const half8*)(qptr + cc * 32);

    const int bsK = b * 2 + (s ^ 1);
    const uint4* Ksrc = (const uint4*)(Kh + (size_t)bsK * NTOK * CDIM);
    const uint4* Vsrc = (const uint4*)(Vt + (size_t)bs * CDIM * NTOK);

    float m_run[4] = {-1e30f, -1e30f, -1e30f, -1e30f};
    float l_run[4] = {0.f, 0.f, 0.f, 0.f};
    f32x4 Oacc[16];
    const f32x4 fz = {0.f, 0.f, 0.f, 0.f};
#pragma unroll
    for (int ct = 0; ct < 16; ct++) Oacc[ct] = fz;

    for (int kt = 0; kt < 64; kt++) {
        const int m0 = kt * 64;
        __syncthreads();   // everyone done reading previous K/V tiles
        // stage K tile [64 m][256 c]: 2048 16B chunks
#pragma unroll
        for (int i = 0; i < 8; i++) {
            int id = t + 256 * i;
            int r = id >> 5, c = id & 31;
            *(uint4*)&Kl[r][c * 8] = Ksrc[(size_t)(m0 + r) * 32 + c];
        }
        // stage V tile [256 c][64 m]: 2048 16B chunks
#pragma unroll
        for (int i = 0; i < 8; i++) {
            int id = t + 256 * i;
            int c = id >> 3, mc = id & 7;
            *(uint4*)&Vl[c][mc * 8] = Vsrc[(size_t)c * (NTOK / 8) + (m0 >> 3) + mc];
        }
        __syncthreads();

        // S = Q K^T  (wave: 16 n x 64 m)
        f32x4 sf[4];
#pragma unroll
        for (int mt = 0; mt < 4; mt++) sf[mt] = fz;
#pragma unroll
        for (int cc = 0; cc < 8; cc++) {
#pragma unroll
            for (int mt = 0; mt < 4; mt++) {
                half8 kf = *(const half8*)&Kl[mt * 16 + (lane & 15)][cc * 32 + (lane >> 4) * 8];
                sf[mt] = __builtin_amdgcn_mfma_f32_16x16x32_f16(qf[cc], kf, sf[mt], 0, 0, 0);
            }
        }

        // online softmax (rows 4*(lane>>4)+r within wave tile, 16 lanes/row)
        float scale[4];
#pragma unroll
        for (int r = 0; r < 4; r++) {
            float mx = fmaxf(fmaxf(sf[0][r], sf[1][r]), fmaxf(sf[2][r], sf[3][r]));
            mx = fmaxf(mx, __shfl_xor(mx, 1));
            mx = fmaxf(mx, __shfl_xor(mx, 2));
            mx = fmaxf(mx, __shfl_xor(mx, 4));
            mx = fmaxf(mx, __shfl_xor(mx, 8));
            float nm = fmaxf(m_run[r], mx);
            scale[r] = __expf(m_run[r] - nm);
            m_run[r] = nm;
            float sum = 0.f;
#pragma unroll
            for (int mt = 0; mt < 4; mt++) {
                float p = __expf(sf[mt][r] - nm);
                sf[mt][r] = p;
                sum += p;
            }
            sum += __shfl_xor(sum, 1);
            sum += __shfl_xor(sum, 2);
            sum += __shfl_xor(sum, 4);
            sum += __shfl_xor(sum, 8);
            l_run[r] = l_run[r] * scale[r] + sum;
        }

        // P -> LDS (wave-private rows) to remap D-frag -> A-frag
#pragma unroll
        for (int mt = 0; mt < 4; mt++) {
#pragma unroll
            for (int r = 0; r < 4; r++) {
                Pl[16 * w + (lane >> 4) * 4 + r][mt * 16 + (lane & 15)] = (_Float16)sf[mt][r];
            }
        }

        // rescale O
#pragma unroll
        for (int ct = 0; ct < 16; ct++) {
#pragma unroll
            for (int r = 0; r < 4; r++) Oacc[ct][r] *= scale[r];
        }

        // O += P V   (K-dim = m, two 32-chunks)
#pragma unroll
        for (int h = 0; h < 2; h++) {
            half8 pa = *(const half8*)&Pl[16 * w + (lane & 15)][h * 32 + (lane >> 4) * 8];
#pragma unroll
            for (int ct = 0; ct < 16; ct++) {
                half8 vf = *(const half8*)&Vl[ct * 16 + (lane & 15)][h * 32 + (lane >> 4) * 8];
                Oacc[ct] = __builtin_amdgcn_mfma_f32_16x16x32_f16(pa, vf, Oacc[ct], 0, 0, 0);
            }
        }
    }

    __syncthreads();   // done with Kl/Vl — reuse as Ol
    float inv[4];
#pragma unroll
    for (int r = 0; r < 4; r++) inv[r] = 1.0f / l_run[r];
#pragma unroll
    for (int ct = 0; ct < 16; ct++) {
#pragma unroll
        for (int r = 0; r < 4; r++) {
            Ol[ct * 16 + (lane & 15)][16 * w + (lane >> 4) * 4 + r] = Oacc[ct][r] * inv[r];
        }
    }
    __syncthreads();
    float* obase = out + (size_t)(s * 4 + b) * CDIM * NTOK + n0;
#pragma unroll
    for (int i = 0; i < 16; i++) {
        int id = t + 256 * i;
        int c = id >> 4, n4 = (id & 15) * 4;
        *(float4*)(obase + (size_t)c * NTOK + n4) = *(const float4*)&Ol[c][n4];
    }
}

// ---------------------------------------------------------------------------
extern "C" void kernel_launch(void* const* d_in, const int* in_sizes, int n_in,
                              void* d_out, int out_size, void* d_ws, size_t ws_size,
                              hipStream_t stream) {
    const float* x1 = (const float*)d_in[0];
    const float* x2 = (const float*)d_in[1];
    const float* Wq = (const float*)d_in[2];
    const float* bq = (const float*)d_in[3];
    const float* Wk = (const float*)d_in[4];
    const float* bk = (const float*)d_in[5];
    const float* Wv = (const float*)d_in[6];
    const float* bv = (const float*)d_in[7];

    // workspace: Qh | Kh | Vt, each 8*4096*256 fp16 = 16 MB  (total 48 MB)
    _Float16* Qh = (_Float16*)d_ws;
    _Float16* Kh = Qh + (size_t)8 * NTOK * CDIM;
    _Float16* Vt = Kh + (size_t)8 * NTOK * CDIM;

    proj_kernel<<<dim3(512), dim3(256), 0, stream>>>(x1, x2, Wq, bq, Wk, bk, Wv, bv, Qh, Kh, Vt);
    flash_kernel<<<dim3(512), dim3(256), 0, stream>>>(Qh, Kh, Vt, (float*)d_out);
}